// Round 4
// baseline (112.743 us; speedup 1.0000x reference)
//
#include <hip/hip_runtime.h>
#include <hip/hip_bf16.h>
#include <stdint.h>

// Problem constants (fixed by setup_inputs)
#define B_   8
#define S_   2048
#define C_   768
#define HID_ 768
#define H_   12
#define KW   9
#define D_   64
#define M_   (B_ * S_)   // 16384 rows
#define PADW 4           // KW/2
#define HK_  108         // H_*KW
#define NPAD 128         // padded N for GEMM2

typedef __attribute__((ext_vector_type(4))) float  floatx4;
typedef __attribute__((ext_vector_type(8))) __bf16 bf16x8;

#define GLD_LDS16(gptr, lptr)                                                  \
    __builtin_amdgcn_global_load_lds(                                          \
        (__attribute__((address_space(1))) void*)(gptr),                       \
        (__attribute__((address_space(3))) void*)(lptr), 16, 0, 0)

#define WAITVM4() do { asm volatile("s_waitcnt vmcnt(4)" ::: "memory"); \
                       __builtin_amdgcn_sched_barrier(0); } while (0)
#define WAITVM0() do { asm volatile("s_waitcnt vmcnt(0)" ::: "memory"); \
                       __builtin_amdgcn_sched_barrier(0); } while (0)

// ---------------------------------------------------------------------------
// Kernel 0: convert pw_weight and attn_W (zero-padded to 128 rows) to bf16
// ---------------------------------------------------------------------------
__global__ __launch_bounds__(256) void convert_w_kernel(
    const float* __restrict__ pwW, const float* __restrict__ attnW,
    __hip_bfloat16* __restrict__ pwWb, __hip_bfloat16* __restrict__ attnWb)
{
    int i = blockIdx.x * 256 + threadIdx.x;           // grid covers C_*HID_
    if (i < C_ * HID_) pwWb[i] = __float2bfloat16(pwW[i]);
    if (i < NPAD * HID_) {
        int n = i / HID_;
        float v = (n < HK_) ? attnW[i] : 0.0f;
        attnWb[i] = __float2bfloat16(v);
    }
}

// ---------------------------------------------------------------------------
// Kernel 1: depthwise conv1d (K=9, pad 4), sliding-window version.
// ---------------------------------------------------------------------------
#define TSD 16

__global__ __launch_bounds__(256) void dwconv_kernel(
    const float* __restrict__ hidden, const float* __restrict__ dw_w,
    __hip_bfloat16* __restrict__ dw_out)
{
    int idx  = blockIdx.x * 256 + threadIdx.x;   // [0, 196608)
    int hq   = idx % (HID_ / 4);                 // 0..191
    int rest = idx / (HID_ / 4);                 // 0..1023
    int sc   = rest % (S_ / TSD);                // 0..127
    int b    = rest / (S_ / TSD);                // 0..7
    int h    = hq * 4;
    int s0   = sc * TSD;
    size_t base = (size_t)b * S_ * HID_ + h;     // row-0 addr for this (b, h)

    float w[36];
    const float4* wp = reinterpret_cast<const float4*>(dw_w + (size_t)h * KW);
#pragma unroll
    for (int i = 0; i < 9; ++i) {
        float4 t = wp[i];
        w[4 * i + 0] = t.x; w[4 * i + 1] = t.y;
        w[4 * i + 2] = t.z; w[4 * i + 3] = t.w;
    }

    float4 win[KW];
#pragma unroll
    for (int k = 0; k < 8; ++k) {
        int sp = s0 + k - PADW;
        float4 v = {0.f, 0.f, 0.f, 0.f};
        if ((unsigned)sp < (unsigned)S_)
            v = *reinterpret_cast<const float4*>(&hidden[base + (size_t)sp * HID_]);
        win[k] = v;
    }

#pragma unroll
    for (int i = 0; i < TSD; ++i) {
        int sp = s0 + i + PADW;
        float4 nv = {0.f, 0.f, 0.f, 0.f};
        if ((unsigned)sp < (unsigned)S_)
            nv = *reinterpret_cast<const float4*>(&hidden[base + (size_t)sp * HID_]);
        win[8] = nv;

        float a0 = 0.f, a1 = 0.f, a2 = 0.f, a3 = 0.f;
#pragma unroll
        for (int k = 0; k < KW; ++k) {
            a0 += win[k].x * w[k];
            a1 += win[k].y * w[9 + k];
            a2 += win[k].z * w[18 + k];
            a3 += win[k].w * w[27 + k];
        }
        union { __hip_bfloat16 bv[4]; uint2 u; } o;
        o.bv[0] = __float2bfloat16(a0);
        o.bv[1] = __float2bfloat16(a1);
        o.bv[2] = __float2bfloat16(a2);
        o.bv[3] = __float2bfloat16(a3);
        *reinterpret_cast<uint2*>(&dw_out[base + (size_t)(s0 + i) * HID_]) = o.u;

#pragma unroll
        for (int k = 0; k < 8; ++k) win[k] = win[k + 1];
    }
}

// ---------------------------------------------------------------------------
// GEMM1, 8-phase 256x256 template (T1+T2+T3+T4+T5), K=768 (12 K-tiles).
// 8 waves as 2M x 4N; per-wave output = strips: rows {wr*64..+64} in each
// A-half, cols {wc*32..+32} in each B-half -> every phase reads exactly one
// A-half and one B-half (workgroup-uniform).
// LDS: [buf][half][128 rows][64 cols] bf16 per operand, 128 KiB total.
// Swizzle: LDS (row, slot16) holds global (row, slot16 ^ (row&7));
// gload_lds dest linear, source pre-swizzled, ds_read XORs the same way.
// Schedule (derived; write-safe + read-safe with vmcnt(4) at p4/p8):
//   p1:(A0,B0)+stg B0(2i+1)  p2:(A0,B1)+stg A1(2i+1)
//   p3:(A1,B1)+stg A0(2i+2)  p4:(A1,B0)+stg B1(2i+2)+vmcnt(4)
//   p5-p8 same on buf1, staging B0/A1(2i+2), A0/B1(2i+3), vmcnt(4)@p8
// Last iteration: skip tile>=12 stages, vmcnt(0) at p4.
// ---------------------------------------------------------------------------
__global__ __launch_bounds__(512, 2) void gemm1_8phase_kernel(
    const __hip_bfloat16* __restrict__ A,
    const __hip_bfloat16* __restrict__ Bt,
    const float* __restrict__ bias,
    const float* __restrict__ query,
    __hip_bfloat16* __restrict__ outB)
{
    __shared__ __align__(16) __hip_bfloat16 Ash[2][2][128 * 64];
    __shared__ __align__(16) __hip_bfloat16 Bsh[2][2][128 * 64];

    const int t    = threadIdx.x;
    const int lane = t & 63;
    const int wave = t >> 6;          // 0..7
    const int wr   = wave >> 2;       // 0..1
    const int wc   = wave & 3;        // 0..3
    const int l16  = lane & 15, lq = lane >> 4;

    // XCD-chunked bijective swizzle (192 blocks, 24/XCD)
    const int bid = (int)blockIdx.x;
    const int wg  = (bid & 7) * 24 + (bid >> 3);
    const int tm  = wg / 3, tn = wg % 3;
    const int row0 = tm * 256, col0 = tn * 256;

    // staging lane constants
    const int srow    = wave * 8 + (lane >> 3);            // 0..63
    const int srcslot = (lane & 7) ^ ((lane >> 3) & 7);    // pre-swizzled source slot
    const __hip_bfloat16* aSrc = A  + (size_t)(row0 + srow) * HID_ + srcslot * 8;
    const __hip_bfloat16* bSrc = Bt + (size_t)(col0 + srow) * HID_ + srcslot * 8;

    floatx4 acc[2][2][4][2];
#pragma unroll
    for (int a = 0; a < 2; ++a)
#pragma unroll
    for (int b = 0; b < 2; ++b)
#pragma unroll
    for (int m = 0; m < 4; ++m)
#pragma unroll
    for (int n = 0; n < 2; ++n) acc[a][b][m][n] = (floatx4){0.f, 0.f, 0.f, 0.f};

#define STG_A(tile, h) do {                                                    \
    const __hip_bfloat16* _g = aSrc + (size_t)(h) * 128 * HID_ + (tile) * 64;  \
    char* _l = (char*)(&Ash[(tile) & 1][h][0]) + wave * 1024;                  \
    GLD_LDS16(_g, _l);                                                         \
    GLD_LDS16(_g + 64 * HID_, _l + 8192);                                      \
} while (0)

#define STG_B(tile, h) do {                                                    \
    const __hip_bfloat16* _g = bSrc + (size_t)(h) * 128 * HID_ + (tile) * 64;  \
    char* _l = (char*)(&Bsh[(tile) & 1][h][0]) + wave * 1024;                  \
    GLD_LDS16(_g, _l);                                                         \
    GLD_LDS16(_g + 64 * HID_, _l + 8192);                                      \
} while (0)

#define PHASE(buf, mh, nh, STAGES, BOUNDARY) do {                              \
    bf16x8 av[4][2], bv[2][2];                                                 \
    const char* _ab = (const char*)(&Ash[buf][mh][0]);                         \
    const char* _bb = (const char*)(&Bsh[buf][nh][0]);                         \
    _Pragma("unroll") for (int _m = 0; _m < 4; ++_m) {                         \
        const int _r = wr * 64 + _m * 16 + l16;                                \
        _Pragma("unroll") for (int _k = 0; _k < 2; ++_k)                       \
            av[_m][_k] = *(const bf16x8*)(_ab + _r * 128 +                     \
                ((_k * 64 + lq * 16) ^ ((l16 & 7) << 4)));                     \
    }                                                                          \
    _Pragma("unroll") for (int _n = 0; _n < 2; ++_n) {                         \
        const int _r = wc * 32 + _n * 16 + l16;                                \
        _Pragma("unroll") for (int _k = 0; _k < 2; ++_k)                       \
            bv[_n][_k] = *(const bf16x8*)(_bb + _r * 128 +                     \
                ((_k * 64 + lq * 16) ^ ((l16 & 7) << 4)));                     \
    }                                                                          \
    STAGES;                                                                    \
    __builtin_amdgcn_s_barrier();                                              \
    asm volatile("s_waitcnt lgkmcnt(0)" ::: "memory");                         \
    __builtin_amdgcn_sched_barrier(0);                                         \
    __builtin_amdgcn_s_setprio(1);                                             \
    _Pragma("unroll") for (int _m = 0; _m < 4; ++_m)                           \
        _Pragma("unroll") for (int _n = 0; _n < 2; ++_n)                       \
            _Pragma("unroll") for (int _k = 0; _k < 2; ++_k)                   \
                acc[mh][nh][_m][_n] = __builtin_amdgcn_mfma_f32_16x16x32_bf16( \
                    av[_m][_k], bv[_n][_k], acc[mh][nh][_m][_n], 0, 0, 0);     \
    __builtin_amdgcn_s_setprio(0);                                             \
    BOUNDARY;                                                                  \
    __builtin_amdgcn_s_barrier();                                              \
} while (0)

    // prologue: tile0 all 4 halves, then A0(1), B1(1); drain to newest-2
    STG_A(0, 0);
    STG_B(0, 1);
    STG_B(0, 0);
    STG_A(0, 1);
    STG_A(1, 0);
    STG_B(1, 1);
    WAITVM4();
    __builtin_amdgcn_s_barrier();

    for (int it = 0; it < 6; ++it) {
        const int t1 = 2 * it + 1, t2 = 2 * it + 2, t3 = 2 * it + 3;
        const bool nl = (it < 5);
        PHASE(0, 0, 0, { STG_B(t1, 0); }, {});
        PHASE(0, 0, 1, { STG_A(t1, 1); }, {});
        PHASE(0, 1, 1, { if (nl) STG_A(t2, 0); }, {});
        PHASE(0, 1, 0, { if (nl) STG_B(t2, 1); },
              { if (nl) { WAITVM4(); } else { WAITVM0(); } });
        PHASE(1, 0, 0, { if (nl) STG_B(t2, 0); }, {});
        PHASE(1, 0, 1, { if (nl) STG_A(t2, 1); }, {});
        PHASE(1, 1, 1, { if (nl) STG_A(t3, 0); }, {});
        PHASE(1, 1, 0, { if (nl) STG_B(t3, 1); }, { if (nl) WAITVM4(); });
    }

    // epilogue: out = (acc + bias[col]) * query[row,col], bf16 store
#pragma unroll
    for (int mh = 0; mh < 2; ++mh)
#pragma unroll
    for (int nh = 0; nh < 2; ++nh)
#pragma unroll
    for (int n = 0; n < 2; ++n) {
        const int col = col0 + nh * 128 + wc * 32 + n * 16 + l16;
        const float bvv = bias[col];
#pragma unroll
        for (int m = 0; m < 4; ++m) {
#pragma unroll
            for (int j = 0; j < 4; ++j) {
                const int row = row0 + mh * 128 + wr * 64 + m * 16 + lq * 4 + j;
                float v = (acc[mh][nh][m][n][j] + bvv) * query[(size_t)row * C_ + col];
                outB[(size_t)row * C_ + col] = __float2bfloat16(v);
            }
        }
    }
#undef STG_A
#undef STG_B
#undef PHASE
}

// ---------------------------------------------------------------------------
// GEMM2 (small): C[M,128] = A[M,768] * Bt[128,768]^T, m97-style 64x64 tile
// out_f32 = acc (ld = NPAD)
// ---------------------------------------------------------------------------
#define BKK 64

__global__ __launch_bounds__(256) void gemm2_kernel(
    const __hip_bfloat16* __restrict__ A,
    const __hip_bfloat16* __restrict__ Bt,
    float* __restrict__ outF,
    int ntN)
{
    constexpr int TBM = 64;
    constexpr int MF = TBM / 32;         // 2
    __shared__ __align__(16) __hip_bfloat16 Alds[TBM * BKK];
    __shared__ __align__(16) __hip_bfloat16 Blds[64 * BKK];

    const int t    = threadIdx.x;
    const int lane = t & 63;
    const int wave = t >> 6;
    const int wr   = wave >> 1, wc = wave & 1;
    const int l16  = lane & 15, lq = lane >> 4;

    const int nwg  = (int)gridDim.x;
    const int chunk = nwg >> 3;
    const int wg   = ((int)blockIdx.x & 7) * chunk + ((int)blockIdx.x >> 3);

    const int tm   = wg / ntN;
    const int tn   = wg % ntN;
    const int row0 = tm * TBM;
    const int col0 = tn * 64;

    const int K = HID_;  // 768

    floatx4 acc[MF][2];
#pragma unroll
    for (int i = 0; i < MF; ++i)
#pragma unroll
        for (int j = 0; j < 2; ++j) acc[i][j] = (floatx4){0.f, 0.f, 0.f, 0.f};

    const int srow = t >> 3;        // 0..31
    const int scol = (t & 7) * 8;   // element offset within BK
    char* aBase = (char*)Alds + wave * 1024;
    char* bBase = (char*)Blds + wave * 1024;

    for (int kt = 0; kt < K; kt += BKK) {
#pragma unroll
        for (int i = 0; i < MF; ++i) {
            const __hip_bfloat16* ga = A + (size_t)(row0 + i * 32 + srow) * K + kt + scol;
            GLD_LDS16(ga, aBase + i * 4096);
        }
#pragma unroll
        for (int i = 0; i < 2; ++i) {
            const __hip_bfloat16* gb = Bt + (size_t)(col0 + i * 32 + srow) * K + kt + scol;
            GLD_LDS16(gb, bBase + i * 4096);
        }
        __syncthreads();

        const bf16x8* A8 = reinterpret_cast<const bf16x8*>(Alds);
        const bf16x8* B8 = reinterpret_cast<const bf16x8*>(Blds);
#pragma unroll
        for (int ks = 0; ks < 2; ++ks) {
            bf16x8 av[MF], bv[2];
#pragma unroll
            for (int m = 0; m < MF; ++m)
                av[m] = A8[(wr * (TBM / 2) + m * 16 + l16) * 8 + ks * 4 + lq];
#pragma unroll
            for (int n = 0; n < 2; ++n)
                bv[n] = B8[(wc * 32 + n * 16 + l16) * 8 + ks * 4 + lq];
#pragma unroll
            for (int m = 0; m < MF; ++m)
#pragma unroll
                for (int n = 0; n < 2; ++n)
                    acc[m][n] = __builtin_amdgcn_mfma_f32_16x16x32_bf16(
                        av[m], bv[n], acc[m][n], 0, 0, 0);
        }
        __syncthreads();
    }

    const int orow0 = row0 + wr * (TBM / 2);
    const int ocol0 = col0 + wc * 32;
#pragma unroll
    for (int m = 0; m < MF; ++m)
#pragma unroll
        for (int n = 0; n < 2; ++n) {
            const int col = ocol0 + n * 16 + l16;
#pragma unroll
            for (int j = 0; j < 4; ++j) {
                const int row = orow0 + m * 16 + lq * 4 + j;
                outF[(size_t)row * NPAD + col] = acc[m][n][j];
            }
        }
}

// ---------------------------------------------------------------------------
// Kernel 4: double softmax over K=9 per (m, h); adds attn_b first
// ---------------------------------------------------------------------------
__global__ __launch_bounds__(256) void softmax2_kernel(
    const float* __restrict__ logits, const float* __restrict__ attn_b,
    float* __restrict__ filt)
{
    int r = blockIdx.x * 256 + threadIdx.x;   // [0, M_*H_)
    int h = r % H_;
    int m = r / H_;

    float v[KW];
#pragma unroll
    for (int k = 0; k < KW; ++k)
        v[k] = logits[(size_t)m * NPAD + h * KW + k] + attn_b[h * KW + k];

#pragma unroll
    for (int pass = 0; pass < 2; ++pass) {
        float mx = v[0];
#pragma unroll
        for (int k = 1; k < KW; ++k) mx = fmaxf(mx, v[k]);
        float s = 0.f;
#pragma unroll
        for (int k = 0; k < KW; ++k) { v[k] = __expf(v[k] - mx); s += v[k]; }
        float inv = 1.f / s;
#pragma unroll
        for (int k = 0; k < KW; ++k) v[k] *= inv;
    }
#pragma unroll
    for (int k = 0; k < KW; ++k) filt[(size_t)r * KW + k] = v[k];
}

// ---------------------------------------------------------------------------
// Kernel 5: light conv, sliding-window version.
// ---------------------------------------------------------------------------
#define TSL 16
#define SCHK 256   // s per block (16 s-groups x TSL)

__global__ __launch_bounds__(256) void lightconv_kernel(
    const float* __restrict__ value, const float* __restrict__ filt,
    float* __restrict__ out)
{
    __shared__ float fl[SCHK * KW];   // 2304 floats

    const int tid = threadIdx.x;
    const int blk = blockIdx.x;                   // [0, 768)
    const int nSC = S_ / SCHK;                    // 8
    const int b   = blk / (H_ * nSC);
    const int rem = blk % (H_ * nSC);
    const int h   = rem / nSC;
    const int sch = rem % nSC;
    const int S0  = sch * SCHK;

    {
        const size_t r0 = ((size_t)b * S_ + S0) * H_ + h;   // filt row of s=S0
#pragma unroll
        for (int i = 0; i < 9; ++i) {
            int j  = tid + 256 * i;               // 0..2303
            int so = j / KW;
            int k  = j - so * KW;
            fl[j] = filt[(r0 + (size_t)so * H_) * KW + k];
        }
    }
    __syncthreads();

    const int d4 = tid & 15;
    const int sg = tid >> 4;                      // 0..15
    const int s0 = S0 + sg * TSL;
    const size_t vbase = (size_t)b * S_ * C_ + h * D_ + d4 * 4;
    const float* flrow = &fl[(sg * TSL) * KW];

    float4 win[KW];
#pragma unroll
    for (int k = 0; k < 8; ++k) {
        int sp = s0 + k - PADW;
        float4 v = {0.f, 0.f, 0.f, 0.f};
        if ((unsigned)sp < (unsigned)S_)
            v = *reinterpret_cast<const float4*>(&value[vbase + (size_t)sp * C_]);
        win[k] = v;
    }

#pragma unroll
    for (int i = 0; i < TSL; ++i) {
        int sp = s0 + i + PADW;
        float4 nv = {0.f, 0.f, 0.f, 0.f};
        if ((unsigned)sp < (unsigned)S_)
            nv = *reinterpret_cast<const float4*>(&value[vbase + (size_t)sp * C_]);
        win[8] = nv;

        float4 acc = {0.f, 0.f, 0.f, 0.f};
#pragma unroll
        for (int k = 0; k < KW; ++k) {
            float f = flrow[i * KW + k];
            acc.x += win[k].x * f;
            acc.y += win[k].y * f;
            acc.z += win[k].z * f;
            acc.w += win[k].w * f;
        }
        *reinterpret_cast<float4*>(&out[vbase + (size_t)(s0 + i) * C_]) = acc;

#pragma unroll
        for (int k = 0; k < 8; ++k) win[k] = win[k + 1];
    }
}

// ---------------------------------------------------------------------------
extern "C" void kernel_launch(void* const* d_in, const int* in_sizes, int n_in,
                              void* d_out, int out_size, void* d_ws, size_t ws_size,
                              hipStream_t stream)
{
    const float* query  = (const float*)d_in[0];
    const float* value  = (const float*)d_in[1];
    const float* hidden = (const float*)d_in[2];
    const float* dw_w   = (const float*)d_in[3];
    const float* pw_w   = (const float*)d_in[4];
    const float* sep_b  = (const float*)d_in[5];
    const float* attn_W = (const float*)d_in[6];
    const float* attn_b = (const float*)d_in[7];
    float* out = (float*)d_out;

    // workspace layout (all regions fully rewritten every call)
    char* ws = (char*)d_ws;
    __hip_bfloat16* dwb    = (__hip_bfloat16*)(ws);              // 25,165,824 B
    __hip_bfloat16* cab    = (__hip_bfloat16*)(ws + 25165824);   // 25,165,824 B
    __hip_bfloat16* pwWb   = (__hip_bfloat16*)(ws + 50331648);   //  1,179,648 B
    __hip_bfloat16* attnWb = (__hip_bfloat16*)(ws + 51511296);   //    196,608 B
    float*          logits = (float*)(ws + 51707904);            //  8,388,608 B
    float*          filt   = (float*)(ws + 60096512);            //  7,077,888 B
    // total: 67,174,400 B

    convert_w_kernel<<<(C_ * HID_) / 256, 256, 0, stream>>>(pw_w, attn_W, pwWb, attnWb);

    dwconv_kernel<<<(M_ * (HID_ / 4)) / (256 * TSD), 256, 0, stream>>>(hidden, dw_w, dwb);

    // GEMM1: 256x256 8-phase, grid 64*3 = 192 blocks of 512 threads
    gemm1_8phase_kernel<<<(M_ / 256) * (C_ / 256), 512, 0, stream>>>(
        dwb, pwWb, sep_b, query, cab);

    // GEMM2: 64x64 tiles -> 256*2 = 512 blocks (2/CU)
    gemm2_kernel<<<(M_ / 64) * (NPAD / 64), 256, 0, stream>>>(
        cab, attnWb, logits, NPAD / 64);

    softmax2_kernel<<<(M_ * H_) / 256, 256, 0, stream>>>(logits, attn_b, filt);

    lightconv_kernel<<<B_ * H_ * (S_ / SCHK), 256, 0, stream>>>(value, filt, out);
}

// Round 5
// 108.567 us; speedup vs baseline: 1.0385x; 1.0385x over previous
//
#include <hip/hip_runtime.h>
#include <hip/hip_bf16.h>
#include <stdint.h>

// Problem constants (fixed by setup_inputs)
#define B_   8
#define S_   2048
#define C_   768
#define HID_ 768
#define H_   12
#define KW   9
#define D_   64
#define M_   (B_ * S_)   // 16384 rows
#define PADW 4           // KW/2
#define HK_  108         // H_*KW
#define NPAD 128         // padded N for GEMM2

typedef __attribute__((ext_vector_type(4))) float  floatx4;
typedef __attribute__((ext_vector_type(8))) __bf16 bf16x8;

#define GLD_LDS16(gptr, lptr)                                                  \
    __builtin_amdgcn_global_load_lds(                                          \
        (__attribute__((address_space(1))) void*)(gptr),                       \
        (__attribute__((address_space(3))) void*)(lptr), 16, 0, 0)

#define WAITVM4() do { asm volatile("s_waitcnt vmcnt(4)" ::: "memory"); \
                       __builtin_amdgcn_sched_barrier(0); } while (0)
#define WAITVM0() do { asm volatile("s_waitcnt vmcnt(0)" ::: "memory"); \
                       __builtin_amdgcn_sched_barrier(0); } while (0)

// ---------------------------------------------------------------------------
// Kernel 0: convert pw_weight and attn_W (zero-padded to 128 rows) to bf16
// ---------------------------------------------------------------------------
__global__ __launch_bounds__(256) void convert_w_kernel(
    const float* __restrict__ pwW, const float* __restrict__ attnW,
    __hip_bfloat16* __restrict__ pwWb, __hip_bfloat16* __restrict__ attnWb)
{
    int i = blockIdx.x * 256 + threadIdx.x;           // grid covers C_*HID_
    if (i < C_ * HID_) pwWb[i] = __float2bfloat16(pwW[i]);
    if (i < NPAD * HID_) {
        int n = i / HID_;
        float v = (n < HK_) ? attnW[i] : 0.0f;
        attnWb[i] = __float2bfloat16(v);
    }
}

// ---------------------------------------------------------------------------
// Kernel 1: depthwise conv1d (K=9, pad 4), sliding-window version.
// ---------------------------------------------------------------------------
#define TSD 16

__global__ __launch_bounds__(256) void dwconv_kernel(
    const float* __restrict__ hidden, const float* __restrict__ dw_w,
    __hip_bfloat16* __restrict__ dw_out)
{
    int idx  = blockIdx.x * 256 + threadIdx.x;   // [0, 196608)
    int hq   = idx % (HID_ / 4);                 // 0..191
    int rest = idx / (HID_ / 4);                 // 0..1023
    int sc   = rest % (S_ / TSD);                // 0..127
    int b    = rest / (S_ / TSD);                // 0..7
    int h    = hq * 4;
    int s0   = sc * TSD;
    size_t base = (size_t)b * S_ * HID_ + h;     // row-0 addr for this (b, h)

    float w[36];
    const float4* wp = reinterpret_cast<const float4*>(dw_w + (size_t)h * KW);
#pragma unroll
    for (int i = 0; i < 9; ++i) {
        float4 t = wp[i];
        w[4 * i + 0] = t.x; w[4 * i + 1] = t.y;
        w[4 * i + 2] = t.z; w[4 * i + 3] = t.w;
    }

    float4 win[KW];
#pragma unroll
    for (int k = 0; k < 8; ++k) {
        int sp = s0 + k - PADW;
        float4 v = {0.f, 0.f, 0.f, 0.f};
        if ((unsigned)sp < (unsigned)S_)
            v = *reinterpret_cast<const float4*>(&hidden[base + (size_t)sp * HID_]);
        win[k] = v;
    }

#pragma unroll
    for (int i = 0; i < TSD; ++i) {
        int sp = s0 + i + PADW;
        float4 nv = {0.f, 0.f, 0.f, 0.f};
        if ((unsigned)sp < (unsigned)S_)
            nv = *reinterpret_cast<const float4*>(&hidden[base + (size_t)sp * HID_]);
        win[8] = nv;

        float a0 = 0.f, a1 = 0.f, a2 = 0.f, a3 = 0.f;
#pragma unroll
        for (int k = 0; k < KW; ++k) {
            a0 += win[k].x * w[k];
            a1 += win[k].y * w[9 + k];
            a2 += win[k].z * w[18 + k];
            a3 += win[k].w * w[27 + k];
        }
        union { __hip_bfloat16 bv[4]; uint2 u; } o;
        o.bv[0] = __float2bfloat16(a0);
        o.bv[1] = __float2bfloat16(a1);
        o.bv[2] = __float2bfloat16(a2);
        o.bv[3] = __float2bfloat16(a3);
        *reinterpret_cast<uint2*>(&dw_out[base + (size_t)(s0 + i) * HID_]) = o.u;

#pragma unroll
        for (int k = 0; k < 8; ++k) win[k] = win[k + 1];
    }
}

// ---------------------------------------------------------------------------
// GEMM1, 8-phase 256x256 (T1+T2+T3+T4+T5) with zigzag register reuse.
// Quadrant walk per K-tile: (A0,B0)->(A0,B1)->(A1,B1)->(A1,B0); consecutive
// phases change ONE operand, so per-phase ds_reads are {12,4,8,4} (28/K-tile
// per wave) instead of 12 every phase (48) -- av/bv persist across phases.
// Staging schedule identical to the verified round-4 one (race-free):
//   p1:+B0(t1) p2:+A1(t1) p3:+A0(t2) p4:+B1(t2)+vmcnt(4)
//   p5:+B0(t2) p6:+A1(t2) p7:+A0(t3) p8:+B1(t3)+vmcnt(4)
// ---------------------------------------------------------------------------
__global__ __launch_bounds__(512, 2) void gemm1_8phase_kernel(
    const __hip_bfloat16* __restrict__ A,
    const __hip_bfloat16* __restrict__ Bt,
    const float* __restrict__ bias,
    const float* __restrict__ query,
    __hip_bfloat16* __restrict__ outB)
{
    __shared__ __align__(16) __hip_bfloat16 Ash[2][2][128 * 64];
    __shared__ __align__(16) __hip_bfloat16 Bsh[2][2][128 * 64];

    const int t    = threadIdx.x;
    const int lane = t & 63;
    const int wave = t >> 6;          // 0..7
    const int wr   = wave >> 2;       // 0..1
    const int wc   = wave & 3;        // 0..3
    const int l16  = lane & 15, lq = lane >> 4;

    // XCD-chunked bijective swizzle (192 blocks, 24/XCD)
    const int bid = (int)blockIdx.x;
    const int wg  = (bid & 7) * 24 + (bid >> 3);
    const int tm  = wg / 3, tn = wg % 3;
    const int row0 = tm * 256, col0 = tn * 256;

    // staging lane constants
    const int srow    = wave * 8 + (lane >> 3);            // 0..63
    const int srcslot = (lane & 7) ^ ((lane >> 3) & 7);    // pre-swizzled source slot
    const __hip_bfloat16* aSrc = A  + (size_t)(row0 + srow) * HID_ + srcslot * 8;
    const __hip_bfloat16* bSrc = Bt + (size_t)(col0 + srow) * HID_ + srcslot * 8;

    floatx4 acc[2][2][4][2];
#pragma unroll
    for (int a = 0; a < 2; ++a)
#pragma unroll
    for (int b = 0; b < 2; ++b)
#pragma unroll
    for (int m = 0; m < 4; ++m)
#pragma unroll
    for (int n = 0; n < 2; ++n) acc[a][b][m][n] = (floatx4){0.f, 0.f, 0.f, 0.f};

    bf16x8 av[4][2];   // current A-half fragments (persist across phases)
    bf16x8 bv[2][2];   // current B-half fragments (persist across phases)

#define STG_A(tile, h) do {                                                    \
    const __hip_bfloat16* _g = aSrc + (size_t)(h) * 128 * HID_ + (tile) * 64;  \
    char* _l = (char*)(&Ash[(tile) & 1][h][0]) + wave * 1024;                  \
    GLD_LDS16(_g, _l);                                                         \
    GLD_LDS16(_g + 64 * HID_, _l + 8192);                                      \
} while (0)

#define STG_B(tile, h) do {                                                    \
    const __hip_bfloat16* _g = bSrc + (size_t)(h) * 128 * HID_ + (tile) * 64;  \
    char* _l = (char*)(&Bsh[(tile) & 1][h][0]) + wave * 1024;                  \
    GLD_LDS16(_g, _l);                                                         \
    GLD_LDS16(_g + 64 * HID_, _l + 8192);                                      \
} while (0)

#define PHASE(buf, mh, nh, RDA, RDB, STAGES, BOUNDARY) do {                    \
    if (RDA) {                                                                 \
        const char* _ab = (const char*)(&Ash[buf][mh][0]);                     \
        _Pragma("unroll") for (int _m = 0; _m < 4; ++_m) {                     \
            const int _r = wr * 64 + _m * 16 + l16;                            \
            _Pragma("unroll") for (int _k = 0; _k < 2; ++_k)                   \
                av[_m][_k] = *(const bf16x8*)(_ab + _r * 128 +                 \
                    ((_k * 64 + lq * 16) ^ ((l16 & 7) << 4)));                 \
        }                                                                      \
    }                                                                          \
    if (RDB) {                                                                 \
        const char* _bb = (const char*)(&Bsh[buf][nh][0]);                     \
        _Pragma("unroll") for (int _n = 0; _n < 2; ++_n) {                     \
            const int _r = wc * 32 + _n * 16 + l16;                            \
            _Pragma("unroll") for (int _k = 0; _k < 2; ++_k)                   \
                bv[_n][_k] = *(const bf16x8*)(_bb + _r * 128 +                 \
                    ((_k * 64 + lq * 16) ^ ((l16 & 7) << 4)));                 \
        }                                                                      \
    }                                                                          \
    STAGES;                                                                    \
    __builtin_amdgcn_s_barrier();                                              \
    asm volatile("s_waitcnt lgkmcnt(0)" ::: "memory");                         \
    __builtin_amdgcn_sched_barrier(0);                                         \
    __builtin_amdgcn_s_setprio(1);                                             \
    _Pragma("unroll") for (int _m = 0; _m < 4; ++_m)                           \
        _Pragma("unroll") for (int _n = 0; _n < 2; ++_n)                       \
            _Pragma("unroll") for (int _k = 0; _k < 2; ++_k)                   \
                acc[mh][nh][_m][_n] = __builtin_amdgcn_mfma_f32_16x16x32_bf16( \
                    av[_m][_k], bv[_n][_k], acc[mh][nh][_m][_n], 0, 0, 0);     \
    __builtin_amdgcn_s_setprio(0);                                             \
    BOUNDARY;                                                                  \
    __builtin_amdgcn_s_barrier();                                              \
} while (0)

    // prologue: tile0 all 4 halves, then A0(1), B1(1); drain to newest-2
    STG_A(0, 0);
    STG_B(0, 1);
    STG_B(0, 0);
    STG_A(0, 1);
    STG_A(1, 0);
    STG_B(1, 1);
    WAITVM4();
    __builtin_amdgcn_s_barrier();

    for (int it = 0; it < 6; ++it) {
        const int t1 = 2 * it + 1, t2 = 2 * it + 2, t3 = 2 * it + 3;
        const bool nl = (it < 5);
        PHASE(0, 0, 0, 1, 1, { STG_B(t1, 0); }, {});
        PHASE(0, 0, 1, 0, 1, { STG_A(t1, 1); }, {});
        PHASE(0, 1, 1, 1, 0, { if (nl) STG_A(t2, 0); }, {});
        PHASE(0, 1, 0, 0, 1, { if (nl) STG_B(t2, 1); },
              { if (nl) { WAITVM4(); } else { WAITVM0(); } });
        PHASE(1, 0, 0, 1, 1, { if (nl) STG_B(t2, 0); }, {});
        PHASE(1, 0, 1, 0, 1, { if (nl) STG_A(t2, 1); }, {});
        PHASE(1, 1, 1, 1, 0, { if (nl) STG_A(t3, 0); }, {});
        PHASE(1, 1, 0, 0, 1, { if (nl) STG_B(t3, 1); }, { if (nl) WAITVM4(); });
    }

    // epilogue: out = (acc + bias[col]) * query[row,col], bf16 store
#pragma unroll
    for (int mh = 0; mh < 2; ++mh)
#pragma unroll
    for (int nh = 0; nh < 2; ++nh)
#pragma unroll
    for (int n = 0; n < 2; ++n) {
        const int col = col0 + nh * 128 + wc * 32 + n * 16 + l16;
        const float bvv = bias[col];
#pragma unroll
        for (int m = 0; m < 4; ++m) {
#pragma unroll
            for (int j = 0; j < 4; ++j) {
                const int row = row0 + mh * 128 + wr * 64 + m * 16 + lq * 4 + j;
                float v = (acc[mh][nh][m][n][j] + bvv) * query[(size_t)row * C_ + col];
                outB[(size_t)row * C_ + col] = __float2bfloat16(v);
            }
        }
    }
#undef STG_A
#undef STG_B
#undef PHASE
}

// ---------------------------------------------------------------------------
// GEMM2 (small): C[M,128] = A[M,768] * Bt[128,768]^T, m97-style 64x64 tile
// out_f32 = acc (ld = NPAD)
// ---------------------------------------------------------------------------
#define BKK 64

__global__ __launch_bounds__(256) void gemm2_kernel(
    const __hip_bfloat16* __restrict__ A,
    const __hip_bfloat16* __restrict__ Bt,
    float* __restrict__ outF,
    int ntN)
{
    constexpr int TBM = 64;
    constexpr int MF = TBM / 32;         // 2
    __shared__ __align__(16) __hip_bfloat16 Alds[TBM * BKK];
    __shared__ __align__(16) __hip_bfloat16 Blds[64 * BKK];

    const int t    = threadIdx.x;
    const int lane = t & 63;
    const int wave = t >> 6;
    const int wr   = wave >> 1, wc = wave & 1;
    const int l16  = lane & 15, lq = lane >> 4;

    const int nwg  = (int)gridDim.x;
    const int chunk = nwg >> 3;
    const int wg   = ((int)blockIdx.x & 7) * chunk + ((int)blockIdx.x >> 3);

    const int tm   = wg / ntN;
    const int tn   = wg % ntN;
    const int row0 = tm * TBM;
    const int col0 = tn * 64;

    const int K = HID_;  // 768

    floatx4 acc[MF][2];
#pragma unroll
    for (int i = 0; i < MF; ++i)
#pragma unroll
        for (int j = 0; j < 2; ++j) acc[i][j] = (floatx4){0.f, 0.f, 0.f, 0.f};

    const int srow = t >> 3;        // 0..31
    const int scol = (t & 7) * 8;   // element offset within BK
    char* aBase = (char*)Alds + wave * 1024;
    char* bBase = (char*)Blds + wave * 1024;

    for (int kt = 0; kt < K; kt += BKK) {
#pragma unroll
        for (int i = 0; i < MF; ++i) {
            const __hip_bfloat16* ga = A + (size_t)(row0 + i * 32 + srow) * K + kt + scol;
            GLD_LDS16(ga, aBase + i * 4096);
        }
#pragma unroll
        for (int i = 0; i < 2; ++i) {
            const __hip_bfloat16* gb = Bt + (size_t)(col0 + i * 32 + srow) * K + kt + scol;
            GLD_LDS16(gb, bBase + i * 4096);
        }
        __syncthreads();

        const bf16x8* A8 = reinterpret_cast<const bf16x8*>(Alds);
        const bf16x8* B8 = reinterpret_cast<const bf16x8*>(Blds);
#pragma unroll
        for (int ks = 0; ks < 2; ++ks) {
            bf16x8 av[MF], bv[2];
#pragma unroll
            for (int m = 0; m < MF; ++m)
                av[m] = A8[(wr * (TBM / 2) + m * 16 + l16) * 8 + ks * 4 + lq];
#pragma unroll
            for (int n = 0; n < 2; ++n)
                bv[n] = B8[(wc * 32 + n * 16 + l16) * 8 + ks * 4 + lq];
#pragma unroll
            for (int m = 0; m < MF; ++m)
#pragma unroll
                for (int n = 0; n < 2; ++n)
                    acc[m][n] = __builtin_amdgcn_mfma_f32_16x16x32_bf16(
                        av[m], bv[n], acc[m][n], 0, 0, 0);
        }
        __syncthreads();
    }

    const int orow0 = row0 + wr * (TBM / 2);
    const int ocol0 = col0 + wc * 32;
#pragma unroll
    for (int m = 0; m < MF; ++m)
#pragma unroll
        for (int n = 0; n < 2; ++n) {
            const int col = ocol0 + n * 16 + l16;
#pragma unroll
            for (int j = 0; j < 4; ++j) {
                const int row = orow0 + m * 16 + lq * 4 + j;
                outF[(size_t)row * NPAD + col] = acc[m][n][j];
            }
        }
}

// ---------------------------------------------------------------------------
// Kernel 4: double softmax over K=9 per (m, h); adds attn_b first
// ---------------------------------------------------------------------------
__global__ __launch_bounds__(256) void softmax2_kernel(
    const float* __restrict__ logits, const float* __restrict__ attn_b,
    float* __restrict__ filt)
{
    int r = blockIdx.x * 256 + threadIdx.x;   // [0, M_*H_)
    int h = r % H_;
    int m = r / H_;

    float v[KW];
#pragma unroll
    for (int k = 0; k < KW; ++k)
        v[k] = logits[(size_t)m * NPAD + h * KW + k] + attn_b[h * KW + k];

#pragma unroll
    for (int pass = 0; pass < 2; ++pass) {
        float mx = v[0];
#pragma unroll
        for (int k = 1; k < KW; ++k) mx = fmaxf(mx, v[k]);
        float s = 0.f;
#pragma unroll
        for (int k = 0; k < KW; ++k) { v[k] = __expf(v[k] - mx); s += v[k]; }
        float inv = 1.f / s;
#pragma unroll
        for (int k = 0; k < KW; ++k) v[k] *= inv;
    }
#pragma unroll
    for (int k = 0; k < KW; ++k) filt[(size_t)r * KW + k] = v[k];
}

// ---------------------------------------------------------------------------
// Kernel 5: light conv, sliding-window version.
// ---------------------------------------------------------------------------
#define TSL 16
#define SCHK 256   // s per block (16 s-groups x TSL)

__global__ __launch_bounds__(256) void lightconv_kernel(
    const float* __restrict__ value, const float* __restrict__ filt,
    float* __restrict__ out)
{
    __shared__ float fl[SCHK * KW];   // 2304 floats

    const int tid = threadIdx.x;
    const int blk = blockIdx.x;                   // [0, 768)
    const int nSC = S_ / SCHK;                    // 8
    const int b   = blk / (H_ * nSC);
    const int rem = blk % (H_ * nSC);
    const int h   = rem / nSC;
    const int sch = rem % nSC;
    const int S0  = sch * SCHK;

    {
        const size_t r0 = ((size_t)b * S_ + S0) * H_ + h;   // filt row of s=S0
#pragma unroll
        for (int i = 0; i < 9; ++i) {
            int j  = tid + 256 * i;               // 0..2303
            int so = j / KW;
            int k  = j - so * KW;
            fl[j] = filt[(r0 + (size_t)so * H_) * KW + k];
        }
    }
    __syncthreads();

    const int d4 = tid & 15;
    const int sg = tid >> 4;                      // 0..15
    const int s0 = S0 + sg * TSL;
    const size_t vbase = (size_t)b * S_ * C_ + h * D_ + d4 * 4;
    const float* flrow = &fl[(sg * TSL) * KW];

    float4 win[KW];
#pragma unroll
    for (int k = 0; k < 8; ++k) {
        int sp = s0 + k - PADW;
        float4 v = {0.f, 0.f, 0.f, 0.f};
        if ((unsigned)sp < (unsigned)S_)
            v = *reinterpret_cast<const float4*>(&value[vbase + (size_t)sp * C_]);
        win[k] = v;
    }

#pragma unroll
    for (int i = 0; i < TSL; ++i) {
        int sp = s0 + i + PADW;
        float4 nv = {0.f, 0.f, 0.f, 0.f};
        if ((unsigned)sp < (unsigned)S_)
            nv = *reinterpret_cast<const float4*>(&value[vbase + (size_t)sp * C_]);
        win[8] = nv;

        float4 acc = {0.f, 0.f, 0.f, 0.f};
#pragma unroll
        for (int k = 0; k < KW; ++k) {
            float f = flrow[i * KW + k];
            acc.x += win[k].x * f;
            acc.y += win[k].y * f;
            acc.z += win[k].z * f;
            acc.w += win[k].w * f;
        }
        *reinterpret_cast<float4*>(&out[vbase + (size_t)(s0 + i) * C_]) = acc;

#pragma unroll
        for (int k = 0; k < 8; ++k) win[k] = win[k + 1];
    }
}

// ---------------------------------------------------------------------------
extern "C" void kernel_launch(void* const* d_in, const int* in_sizes, int n_in,
                              void* d_out, int out_size, void* d_ws, size_t ws_size,
                              hipStream_t stream)
{
    const float* query  = (const float*)d_in[0];
    const float* value  = (const float*)d_in[1];
    const float* hidden = (const float*)d_in[2];
    const float* dw_w   = (const float*)d_in[3];
    const float* pw_w   = (const float*)d_in[4];
    const float* sep_b  = (const float*)d_in[5];
    const float* attn_W = (const float*)d_in[6];
    const float* attn_b = (const float*)d_in[7];
    float* out = (float*)d_out;

    // workspace layout (all regions fully rewritten every call)
    char* ws = (char*)d_ws;
    __hip_bfloat16* dwb    = (__hip_bfloat16*)(ws);              // 25,165,824 B
    __hip_bfloat16* cab    = (__hip_bfloat16*)(ws + 25165824);   // 25,165,824 B
    __hip_bfloat16* pwWb   = (__hip_bfloat16*)(ws + 50331648);   //  1,179,648 B
    __hip_bfloat16* attnWb = (__hip_bfloat16*)(ws + 51511296);   //    196,608 B
    float*          logits = (float*)(ws + 51707904);            //  8,388,608 B
    float*          filt   = (float*)(ws + 60096512);            //  7,077,888 B
    // total: 67,174,400 B

    convert_w_kernel<<<(C_ * HID_) / 256, 256, 0, stream>>>(pw_w, attn_W, pwWb, attnWb);

    dwconv_kernel<<<(M_ * (HID_ / 4)) / (256 * TSD), 256, 0, stream>>>(hidden, dw_w, dwb);

    // GEMM1: 256x256 8-phase, grid 64*3 = 192 blocks of 512 threads
    gemm1_8phase_kernel<<<(M_ / 256) * (C_ / 256), 512, 0, stream>>>(
        dwb, pwWb, sep_b, query, cab);

    // GEMM2: 64x64 tiles -> 256*2 = 512 blocks (2/CU)
    gemm2_kernel<<<(M_ / 64) * (NPAD / 64), 256, 0, stream>>>(
        cab, attnWb, logits, NPAD / 64);

    softmax2_kernel<<<(M_ * H_) / 256, 256, 0, stream>>>(logits, attn_b, filt);

    lightconv_kernel<<<B_ * H_ * (S_ / SCHK), 256, 0, stream>>>(value, filt, out);
}

// Round 6
// 100.945 us; speedup vs baseline: 1.1169x; 1.0755x over previous
//
#include <hip/hip_runtime.h>
#include <hip/hip_bf16.h>
#include <stdint.h>

// Problem constants (fixed by setup_inputs)
#define B_   8
#define S_   2048
#define C_   768
#define HID_ 768
#define H_   12
#define KW   9
#define D_   64
#define M_   (B_ * S_)   // 16384 rows
#define PADW 4           // KW/2
#define HK_  108         // H_*KW
#define NPAD 128         // padded N for the attn projection

typedef __attribute__((ext_vector_type(4))) float  floatx4;
typedef __attribute__((ext_vector_type(8))) __bf16 bf16x8;

#define GLD_LDS16(gptr, lptr)                                                  \
    __builtin_amdgcn_global_load_lds(                                          \
        (__attribute__((address_space(1))) void*)(gptr),                       \
        (__attribute__((address_space(3))) void*)(lptr), 16, 0, 0)

#define BARR() do { __builtin_amdgcn_s_barrier();                              \
                    __builtin_amdgcn_sched_barrier(0); } while (0)
#define LGKM0() do { asm volatile("s_waitcnt lgkmcnt(0)" ::: "memory");        \
                     __builtin_amdgcn_sched_barrier(0); } while (0)

// ---------------------------------------------------------------------------
// Kernel 0: convert pw_weight and attn_W (zero-padded to 128 rows) to bf16
// ---------------------------------------------------------------------------
__global__ __launch_bounds__(256) void convert_w_kernel(
    const float* __restrict__ pwW, const float* __restrict__ attnW,
    __hip_bfloat16* __restrict__ pwWb, __hip_bfloat16* __restrict__ attnWb)
{
    int i = blockIdx.x * 256 + threadIdx.x;           // grid covers C_*HID_
    if (i < C_ * HID_) pwWb[i] = __float2bfloat16(pwW[i]);
    if (i < NPAD * HID_) {
        int n = i / HID_;
        float v = (n < HK_) ? attnW[i] : 0.0f;
        attnWb[i] = __float2bfloat16(v);
    }
}

// ---------------------------------------------------------------------------
// Kernel 1: depthwise conv1d (K=9, pad 4), sliding-window version.
// ---------------------------------------------------------------------------
#define TSD 16

__global__ __launch_bounds__(256) void dwconv_kernel(
    const float* __restrict__ hidden, const float* __restrict__ dw_w,
    __hip_bfloat16* __restrict__ dw_out)
{
    int idx  = blockIdx.x * 256 + threadIdx.x;   // [0, 196608)
    int hq   = idx % (HID_ / 4);                 // 0..191
    int rest = idx / (HID_ / 4);                 // 0..1023
    int sc   = rest % (S_ / TSD);                // 0..127
    int b    = rest / (S_ / TSD);                // 0..7
    int h    = hq * 4;
    int s0   = sc * TSD;
    size_t base = (size_t)b * S_ * HID_ + h;     // row-0 addr for this (b, h)

    float w[36];
    const float4* wp = reinterpret_cast<const float4*>(dw_w + (size_t)h * KW);
#pragma unroll
    for (int i = 0; i < 9; ++i) {
        float4 t = wp[i];
        w[4 * i + 0] = t.x; w[4 * i + 1] = t.y;
        w[4 * i + 2] = t.z; w[4 * i + 3] = t.w;
    }

    float4 win[KW];
#pragma unroll
    for (int k = 0; k < 8; ++k) {
        int sp = s0 + k - PADW;
        float4 v = {0.f, 0.f, 0.f, 0.f};
        if ((unsigned)sp < (unsigned)S_)
            v = *reinterpret_cast<const float4*>(&hidden[base + (size_t)sp * HID_]);
        win[k] = v;
    }

#pragma unroll
    for (int i = 0; i < TSD; ++i) {
        int sp = s0 + i + PADW;
        float4 nv = {0.f, 0.f, 0.f, 0.f};
        if ((unsigned)sp < (unsigned)S_)
            nv = *reinterpret_cast<const float4*>(&hidden[base + (size_t)sp * HID_]);
        win[8] = nv;

        float a0 = 0.f, a1 = 0.f, a2 = 0.f, a3 = 0.f;
#pragma unroll
        for (int k = 0; k < KW; ++k) {
            a0 += win[k].x * w[k];
            a1 += win[k].y * w[9 + k];
            a2 += win[k].z * w[18 + k];
            a3 += win[k].w * w[27 + k];
        }
        union { __hip_bfloat16 bv[4]; uint2 u; } o;
        o.bv[0] = __float2bfloat16(a0);
        o.bv[1] = __float2bfloat16(a1);
        o.bv[2] = __float2bfloat16(a2);
        o.bv[3] = __float2bfloat16(a3);
        *reinterpret_cast<uint2*>(&dw_out[base + (size_t)(s0 + i) * HID_]) = o.u;

#pragma unroll
        for (int k = 0; k < 8; ++k) win[k] = win[k + 1];
    }
}

// ---------------------------------------------------------------------------
// FUSED kernel: GEMM1 (cab = (dwb@pwW^T + bias) * query, bf16) +
//               GEMM2 (logits = cab @ attnW^T, in-register accumulate) +
//               double softmax -> filt.
// Block = 64 rows of M; 512 threads = 8 waves (2 row-groups x 4 col-groups,
// wave tile 32x32). Loops 6 n-tiles of 128 cols:
//   - 12 x BK=64 double-buffered K-loop: counted vmcnt(3) keeps next tile's
//     3 global_load_lds in flight across the barrier (T4); LDS XOR-swizzled
//     via pre-swizzled global source + XOR'd ds_read (T2, rule 21).
//   - epilogue: (acc1+bias)*query -> bf16 -> P in LDS (XOR-swizzled writes)
//   - gemm2 pass: acc2 += P(LDS) @ attnW-slice(global, L2-hot)
// Finale: acc2 -> LDS -> per-thread 9-wide double softmax -> filt.
// LDS 48 KB: [A dbuf 16K | B dbuf 32K], P aliases A-dbuf, LG aliases B-dbuf.
// ---------------------------------------------------------------------------
__global__ __launch_bounds__(512, 2) void fused_gemm_kernel(
    const __hip_bfloat16* __restrict__ A,     // dwb   [M_][HID_]
    const __hip_bfloat16* __restrict__ Bt,    // pwWb  [C_][HID_]
    const __hip_bfloat16* __restrict__ Wt,    // attnWb[NPAD][C_]
    const float* __restrict__ bias,           // sep_b [C_]
    const float* __restrict__ query,          // [M_][C_]
    const float* __restrict__ attn_b,         // [HK_]
    float* __restrict__ filt)                 // [M_*H_][KW]
{
    __shared__ __align__(16) char lds[49152];
    char* Plds = lds;                         // 16 KB, aliases A dbuf
    float* LG  = (float*)(lds + 16384);       // [64][128] f32, aliases B dbuf

    const int t    = threadIdx.x;
    const int lane = t & 63;
    const int wave = t >> 6;       // 0..7
    const int wr   = wave >> 2;    // 0..1  (row group)
    const int wc   = wave & 3;     // 0..3  (col group)
    const int l16  = lane & 15, lq = lane >> 4;

    const int row0 = (int)blockIdx.x * 64;

    // staging constants: 1 instr = 1 KB = 8 rows of 128 B
    const int sr8     = lane >> 3;                      // 0..7
    const int srcslot = (lane & 7) ^ sr8;               // pre-swizzled source
    const __hip_bfloat16* aS = A + (size_t)(row0 + wave * 8 + sr8) * HID_ + srcslot * 8;

    floatx4 acc2[2][2];
#pragma unroll
    for (int m = 0; m < 2; ++m)
#pragma unroll
        for (int n = 0; n < 2; ++n) acc2[m][n] = (floatx4){0.f, 0.f, 0.f, 0.f};

    for (int nt = 0; nt < 6; ++nt) {
        const __hip_bfloat16* bS =
            Bt + (size_t)(nt * 128 + wave * 8 + sr8) * HID_ + srcslot * 8;

        floatx4 acc1[2][2];
#pragma unroll
        for (int m = 0; m < 2; ++m)
#pragma unroll
            for (int n = 0; n < 2; ++n) acc1[m][n] = (floatx4){0.f, 0.f, 0.f, 0.f};

#define FSTG(kt, buf) do {                                                     \
        GLD_LDS16(aS + (kt) * 64, lds + (buf) * 8192 + wave * 1024);           \
        GLD_LDS16(bS + (kt) * 64, lds + 16384 + (buf) * 16384 + wave * 1024);  \
        GLD_LDS16(bS + 64 * HID_ + (kt) * 64,                                  \
                  lds + 16384 + (buf) * 16384 + 8192 + wave * 1024);           \
    } while (0)

        FSTG(0, 0);
#pragma unroll 2
        for (int kt = 0; kt < 12; ++kt) {
            const int cur = kt & 1;
            if (kt < 11) {
                FSTG(kt + 1, cur ^ 1);
                asm volatile("s_waitcnt vmcnt(3)" ::: "memory");
            } else {
                asm volatile("s_waitcnt vmcnt(0)" ::: "memory");
            }
            __builtin_amdgcn_sched_barrier(0);
            BARR();                       // stage(kt) visible to all waves

            const char* ab = lds + cur * 8192;
            const char* bb = lds + 16384 + cur * 16384;
            bf16x8 av[2][2], bv[2][2];
#pragma unroll
            for (int m = 0; m < 2; ++m) {
                const int r = wr * 32 + m * 16 + l16;
#pragma unroll
                for (int ks = 0; ks < 2; ++ks)
                    av[m][ks] = *(const bf16x8*)(ab + r * 128 +
                        ((ks * 64 + lq * 16) ^ ((l16 & 7) << 4)));
            }
#pragma unroll
            for (int n = 0; n < 2; ++n) {
                const int r = wc * 32 + n * 16 + l16;
#pragma unroll
                for (int ks = 0; ks < 2; ++ks)
                    bv[n][ks] = *(const bf16x8*)(bb + r * 128 +
                        ((ks * 64 + lq * 16) ^ ((l16 & 7) << 4)));
            }
            __builtin_amdgcn_s_setprio(1);
#pragma unroll
            for (int m = 0; m < 2; ++m)
#pragma unroll
                for (int n = 0; n < 2; ++n)
#pragma unroll
                    for (int ks = 0; ks < 2; ++ks)
                        acc1[m][n] = __builtin_amdgcn_mfma_f32_16x16x32_bf16(
                            av[m][ks], bv[n][ks], acc1[m][n], 0, 0, 0);
            __builtin_amdgcn_s_setprio(0);
            LGKM0();                      // reads drained before overwrite
            BARR();
        }
#undef FSTG

        // epilogue: P = (acc1 + bias) * query -> bf16, XOR-swizzled LDS write
#pragma unroll
        for (int m = 0; m < 2; ++m)
#pragma unroll
            for (int n = 0; n < 2; ++n) {
                const int cl   = wc * 32 + n * 16 + l16;
                const int gcol = nt * 128 + cl;
                const float bvv = bias[gcol];
#pragma unroll
                for (int j = 0; j < 4; ++j) {
                    const int row = wr * 32 + m * 16 + lq * 4 + j;
                    float v = (acc1[m][n][j] + bvv) *
                              query[(size_t)(row0 + row) * C_ + gcol];
                    __hip_bfloat16 hb = __float2bfloat16(v);
                    *(uint16_t*)(Plds + row * 256 +
                                 ((cl * 2) ^ ((row & 7) << 4))) =
                        *(uint16_t*)&hb;
                }
            }
        LGKM0();
        BARR();                           // P complete

        // gemm2 pass: acc2 += P[64x128] @ W-slice[128 x 128]^T
#pragma unroll
        for (int kk = 0; kk < 4; ++kk) {
            bf16x8 pv[2], wv[2];
#pragma unroll
            for (int m = 0; m < 2; ++m) {
                const int r = wr * 32 + m * 16 + l16;
                pv[m] = *(const bf16x8*)(Plds + r * 256 +
                    ((kk * 64 + lq * 16) ^ ((l16 & 7) << 4)));
            }
#pragma unroll
            for (int n = 0; n < 2; ++n) {
                const int wrow = wc * 32 + n * 16 + l16;
                wv[n] = *(const bf16x8*)(Wt + (size_t)wrow * C_ +
                                         nt * 128 + kk * 32 + lq * 8);
            }
#pragma unroll
            for (int m = 0; m < 2; ++m)
#pragma unroll
                for (int n = 0; n < 2; ++n)
                    acc2[m][n] = __builtin_amdgcn_mfma_f32_16x16x32_bf16(
                        pv[m], wv[n], acc2[m][n], 0, 0, 0);
        }
        LGKM0();
        BARR();                           // P reads done; next nt may overwrite
    }

    // finale: acc2 -> LG, then per-(row,h) double softmax -> filt
#pragma unroll
    for (int m = 0; m < 2; ++m)
#pragma unroll
        for (int n = 0; n < 2; ++n) {
            const int cl = wc * 32 + n * 16 + l16;
#pragma unroll
            for (int j = 0; j < 4; ++j) {
                const int row = wr * 32 + m * 16 + lq * 4 + j;
                LG[row * 128 + cl] = acc2[m][n][j];
            }
        }
    LGKM0();
    BARR();

    for (int id = t; id < 64 * H_; id += 512) {
        const int row = id / H_;
        const int h   = id - row * H_;
        float v[KW];
#pragma unroll
        for (int k = 0; k < KW; ++k)
            v[k] = LG[row * 128 + h * KW + k] + attn_b[h * KW + k];
#pragma unroll
        for (int pass = 0; pass < 2; ++pass) {
            float mx = v[0];
#pragma unroll
            for (int k = 1; k < KW; ++k) mx = fmaxf(mx, v[k]);
            float s = 0.f;
#pragma unroll
            for (int k = 0; k < KW; ++k) { v[k] = __expf(v[k] - mx); s += v[k]; }
            float inv = 1.f / s;
#pragma unroll
            for (int k = 0; k < KW; ++k) v[k] *= inv;
        }
        const size_t base = ((size_t)(row0 + row) * H_ + h) * KW;
#pragma unroll
        for (int k = 0; k < KW; ++k) filt[base + k] = v[k];
    }
}

// ---------------------------------------------------------------------------
// Kernel 5: light conv, sliding-window version.
// ---------------------------------------------------------------------------
#define TSL 16
#define SCHK 256   // s per block (16 s-groups x TSL)

__global__ __launch_bounds__(256) void lightconv_kernel(
    const float* __restrict__ value, const float* __restrict__ filt,
    float* __restrict__ out)
{
    __shared__ float fl[SCHK * KW];   // 2304 floats

    const int tid = threadIdx.x;
    const int blk = blockIdx.x;                   // [0, 768)
    const int nSC = S_ / SCHK;                    // 8
    const int b   = blk / (H_ * nSC);
    const int rem = blk % (H_ * nSC);
    const int h   = rem / nSC;
    const int sch = rem % nSC;
    const int S0  = sch * SCHK;

    {
        const size_t r0 = ((size_t)b * S_ + S0) * H_ + h;   // filt row of s=S0
#pragma unroll
        for (int i = 0; i < 9; ++i) {
            int j  = tid + 256 * i;               // 0..2303
            int so = j / KW;
            int k  = j - so * KW;
            fl[j] = filt[(r0 + (size_t)so * H_) * KW + k];
        }
    }
    __syncthreads();

    const int d4 = tid & 15;
    const int sg = tid >> 4;                      // 0..15
    const int s0 = S0 + sg * TSL;
    const size_t vbase = (size_t)b * S_ * C_ + h * D_ + d4 * 4;
    const float* flrow = &fl[(sg * TSL) * KW];

    float4 win[KW];
#pragma unroll
    for (int k = 0; k < 8; ++k) {
        int sp = s0 + k - PADW;
        float4 v = {0.f, 0.f, 0.f, 0.f};
        if ((unsigned)sp < (unsigned)S_)
            v = *reinterpret_cast<const float4*>(&value[vbase + (size_t)sp * C_]);
        win[k] = v;
    }

#pragma unroll
    for (int i = 0; i < TSL; ++i) {
        int sp = s0 + i + PADW;
        float4 nv = {0.f, 0.f, 0.f, 0.f};
        if ((unsigned)sp < (unsigned)S_)
            nv = *reinterpret_cast<const float4*>(&value[vbase + (size_t)sp * C_]);
        win[8] = nv;

        float4 acc = {0.f, 0.f, 0.f, 0.f};
#pragma unroll
        for (int k = 0; k < KW; ++k) {
            float f = flrow[i * KW + k];
            acc.x += win[k].x * f;
            acc.y += win[k].y * f;
            acc.z += win[k].z * f;
            acc.w += win[k].w * f;
        }
        *reinterpret_cast<float4*>(&out[vbase + (size_t)(s0 + i) * C_]) = acc;

#pragma unroll
        for (int k = 0; k < 8; ++k) win[k] = win[k + 1];
    }
}

// ---------------------------------------------------------------------------
extern "C" void kernel_launch(void* const* d_in, const int* in_sizes, int n_in,
                              void* d_out, int out_size, void* d_ws, size_t ws_size,
                              hipStream_t stream)
{
    const float* query  = (const float*)d_in[0];
    const float* value  = (const float*)d_in[1];
    const float* hidden = (const float*)d_in[2];
    const float* dw_w   = (const float*)d_in[3];
    const float* pw_w   = (const float*)d_in[4];
    const float* sep_b  = (const float*)d_in[5];
    const float* attn_W = (const float*)d_in[6];
    const float* attn_b = (const float*)d_in[7];
    float* out = (float*)d_out;

    // workspace layout (all regions fully rewritten every call)
    char* ws = (char*)d_ws;
    __hip_bfloat16* dwb    = (__hip_bfloat16*)(ws);              // 25,165,824 B
    __hip_bfloat16* pwWb   = (__hip_bfloat16*)(ws + 25165824);   //  1,179,648 B
    __hip_bfloat16* attnWb = (__hip_bfloat16*)(ws + 26345472);   //    196,608 B
    float*          filt   = (float*)(ws + 26542080);            //  7,077,888 B
    // total: 33,619,968 B

    convert_w_kernel<<<(C_ * HID_) / 256, 256, 0, stream>>>(pw_w, attn_W, pwWb, attnWb);

    dwconv_kernel<<<(M_ * (HID_ / 4)) / (256 * TSD), 256, 0, stream>>>(hidden, dw_w, dwb);

    fused_gemm_kernel<<<M_ / 64, 512, 0, stream>>>(
        dwb, pwWb, attnWb, sep_b, query, attn_b, filt);

    lightconv_kernel<<<B_ * H_ * (S_ / SCHK), 256, 0, stream>>>(value, filt, out);
}

// Round 7
// 94.045 us; speedup vs baseline: 1.1988x; 1.0734x over previous
//
#include <hip/hip_runtime.h>
#include <hip/hip_bf16.h>
#include <stdint.h>

// Problem constants (fixed by setup_inputs)
#define B_   8
#define S_   2048
#define C_   768
#define HID_ 768
#define H_   12
#define KW   9
#define D_   64
#define M_   (B_ * S_)   // 16384 rows
#define PADW 4           // KW/2
#define HK_  108         // H_*KW
#define NPAD 128         // padded N for the attn projection

typedef __attribute__((ext_vector_type(4))) float  floatx4;
typedef __attribute__((ext_vector_type(8))) __bf16 bf16x8;

#define GLD_LDS16(gptr, lptr)                                                  \
    __builtin_amdgcn_global_load_lds(                                          \
        (__attribute__((address_space(1))) void*)(gptr),                       \
        (__attribute__((address_space(3))) void*)(lptr), 16, 0, 0)

#define BARR() do { __builtin_amdgcn_s_barrier();                              \
                    __builtin_amdgcn_sched_barrier(0); } while (0)
#define LGKM0() do { asm volatile("s_waitcnt lgkmcnt(0)" ::: "memory");        \
                     __builtin_amdgcn_sched_barrier(0); } while (0)

// ---------------------------------------------------------------------------
// Kernel 0: convert pw_weight and attn_W (zero-padded to 128 rows) to bf16
// ---------------------------------------------------------------------------
__global__ __launch_bounds__(256) void convert_w_kernel(
    const float* __restrict__ pwW, const float* __restrict__ attnW,
    __hip_bfloat16* __restrict__ pwWb, __hip_bfloat16* __restrict__ attnWb)
{
    int i = blockIdx.x * 256 + threadIdx.x;           // grid covers C_*HID_
    if (i < C_ * HID_) pwWb[i] = __float2bfloat16(pwW[i]);
    if (i < NPAD * HID_) {
        int n = i / HID_;
        float v = (n < HK_) ? attnW[i] : 0.0f;
        attnWb[i] = __float2bfloat16(v);
    }
}

// ---------------------------------------------------------------------------
// Kernel 1: depthwise conv1d (K=9, pad 4), sliding-window version.
// ---------------------------------------------------------------------------
#define TSD 16

__global__ __launch_bounds__(256) void dwconv_kernel(
    const float* __restrict__ hidden, const float* __restrict__ dw_w,
    __hip_bfloat16* __restrict__ dw_out)
{
    int idx  = blockIdx.x * 256 + threadIdx.x;   // [0, 196608)
    int hq   = idx % (HID_ / 4);                 // 0..191
    int rest = idx / (HID_ / 4);                 // 0..1023
    int sc   = rest % (S_ / TSD);                // 0..127
    int b    = rest / (S_ / TSD);                // 0..7
    int h    = hq * 4;
    int s0   = sc * TSD;
    size_t base = (size_t)b * S_ * HID_ + h;     // row-0 addr for this (b, h)

    float w[36];
    const float4* wp = reinterpret_cast<const float4*>(dw_w + (size_t)h * KW);
#pragma unroll
    for (int i = 0; i < 9; ++i) {
        float4 t = wp[i];
        w[4 * i + 0] = t.x; w[4 * i + 1] = t.y;
        w[4 * i + 2] = t.z; w[4 * i + 3] = t.w;
    }

    float4 win[KW];
#pragma unroll
    for (int k = 0; k < 8; ++k) {
        int sp = s0 + k - PADW;
        float4 v = {0.f, 0.f, 0.f, 0.f};
        if ((unsigned)sp < (unsigned)S_)
            v = *reinterpret_cast<const float4*>(&hidden[base + (size_t)sp * HID_]);
        win[k] = v;
    }

#pragma unroll
    for (int i = 0; i < TSD; ++i) {
        int sp = s0 + i + PADW;
        float4 nv = {0.f, 0.f, 0.f, 0.f};
        if ((unsigned)sp < (unsigned)S_)
            nv = *reinterpret_cast<const float4*>(&hidden[base + (size_t)sp * HID_]);
        win[8] = nv;

        float a0 = 0.f, a1 = 0.f, a2 = 0.f, a3 = 0.f;
#pragma unroll
        for (int k = 0; k < KW; ++k) {
            a0 += win[k].x * w[k];
            a1 += win[k].y * w[9 + k];
            a2 += win[k].z * w[18 + k];
            a3 += win[k].w * w[27 + k];
        }
        union { __hip_bfloat16 bv[4]; uint2 u; } o;
        o.bv[0] = __float2bfloat16(a0);
        o.bv[1] = __float2bfloat16(a1);
        o.bv[2] = __float2bfloat16(a2);
        o.bv[3] = __float2bfloat16(a3);
        *reinterpret_cast<uint2*>(&dw_out[base + (size_t)(s0 + i) * HID_]) = o.u;

#pragma unroll
        for (int k = 0; k < 8; ++k) win[k] = win[k + 1];
    }
}

// ---------------------------------------------------------------------------
// FUSED kernel v2: block = 32 rows, 256 threads = 4 waves (1r x 4c),
// wave tile 32x64 (av 4 + bv 8 ds_reads per 16 MFMA = 0.75 ratio).
// 3 n-tiles of 256 cols; per n-tile a 12-step BK=64 double-buffered K-loop
// (counted vmcnt(9): next K-step's 9 global_load_lds stay in flight across
// the barrier). Grid 512 = 2 blocks/CU -> two barrier domains overlap.
// After each n-tile: P = (acc1+bias)*query -> bf16 -> swizzled LDS;
// acc2 += P @ attnW-slice (W direct from global, L2-hot).
// Finale: acc2 -> LDS -> per-(row,h) double softmax -> filt.
// LDS 72 KB: A-dbuf 2x4K @0, B-dbuf 2x32K @8192.
// P (16 KB) aliases B-buf0; LG (16 KB) aliases B-buf1.
// ---------------------------------------------------------------------------
__global__ __launch_bounds__(256, 2) void fused_gemm_kernel(
    const __hip_bfloat16* __restrict__ A,     // dwb   [M_][HID_]
    const __hip_bfloat16* __restrict__ Bt,    // pwWb  [C_][HID_]
    const __hip_bfloat16* __restrict__ Wt,    // attnWb[NPAD][C_]
    const float* __restrict__ bias,           // sep_b [C_]
    const float* __restrict__ query,          // [M_][C_]
    const float* __restrict__ attn_b,         // [HK_]
    float* __restrict__ filt)                 // [M_*H_][KW]
{
    __shared__ __align__(16) char lds[73728];
    char* Plds = lds + 8192;                  // aliases B-buf0 (16 KB used)
    float* LG  = (float*)(lds + 8192 + 32768);// aliases B-buf1: [32][128] f32

    const int t    = threadIdx.x;
    const int lane = t & 63;
    const int wave = t >> 6;       // 0..3  (= col group wc)
    const int l16  = lane & 15, lq = lane >> 4;

    const int row0 = (int)blockIdx.x * 32;

    // staging constants: 1 instr = 1 KB = 8 rows of 128 B
    const int sr8     = lane >> 3;                      // 0..7
    const int srcslot = (lane & 7) ^ sr8;               // pre-swizzled source
    // A: 4 KB/step, 1 instr per wave (rows wave*8 + sr8)
    const __hip_bfloat16* aS = A + (size_t)(row0 + wave * 8 + sr8) * HID_ + srcslot * 8;

    floatx4 acc2[2][2];
#pragma unroll
    for (int m = 0; m < 2; ++m)
#pragma unroll
        for (int n = 0; n < 2; ++n) acc2[m][n] = (floatx4){0.f, 0.f, 0.f, 0.f};

    for (int nt = 0; nt < 3; ++nt) {
        // B: 32 KB/step, 8 instrs per wave (rows wave*64 + i*8 + sr8)
        const __hip_bfloat16* bS =
            Bt + (size_t)(nt * 256 + wave * 64 + sr8) * HID_ + srcslot * 8;

        floatx4 acc1[2][4];
#pragma unroll
        for (int m = 0; m < 2; ++m)
#pragma unroll
            for (int n = 0; n < 4; ++n) acc1[m][n] = (floatx4){0.f, 0.f, 0.f, 0.f};

#define FSTG(kt, buf) do {                                                     \
        GLD_LDS16(aS + (kt) * 64, lds + (buf) * 4096 + wave * 1024);           \
        _Pragma("unroll")                                                      \
        for (int _i = 0; _i < 8; ++_i)                                         \
            GLD_LDS16(bS + (size_t)_i * 8 * HID_ + (kt) * 64,                  \
                      lds + 8192 + (buf) * 32768 + wave * 8192 + _i * 1024);   \
    } while (0)

        FSTG(0, 0);
#pragma unroll 2
        for (int kt = 0; kt < 12; ++kt) {
            const int cur = kt & 1;
            if (kt < 11) {
                FSTG(kt + 1, cur ^ 1);
                asm volatile("s_waitcnt vmcnt(9)" ::: "memory");
            } else {
                asm volatile("s_waitcnt vmcnt(0)" ::: "memory");
            }
            __builtin_amdgcn_sched_barrier(0);
            BARR();                       // stage(kt) visible to all waves

            const char* ab = lds + cur * 4096;
            const char* bb = lds + 8192 + cur * 32768;
            bf16x8 av[2][2], bv[4][2];
#pragma unroll
            for (int m = 0; m < 2; ++m) {
                const int r = m * 16 + l16;
#pragma unroll
                for (int ks = 0; ks < 2; ++ks)
                    av[m][ks] = *(const bf16x8*)(ab + r * 128 +
                        ((ks * 64 + lq * 16) ^ ((l16 & 7) << 4)));
            }
#pragma unroll
            for (int n = 0; n < 4; ++n) {
                const int r = wave * 64 + n * 16 + l16;
#pragma unroll
                for (int ks = 0; ks < 2; ++ks)
                    bv[n][ks] = *(const bf16x8*)(bb + r * 128 +
                        ((ks * 64 + lq * 16) ^ ((l16 & 7) << 4)));
            }
            __builtin_amdgcn_s_setprio(1);
#pragma unroll
            for (int m = 0; m < 2; ++m)
#pragma unroll
                for (int n = 0; n < 4; ++n)
#pragma unroll
                    for (int ks = 0; ks < 2; ++ks)
                        acc1[m][n] = __builtin_amdgcn_mfma_f32_16x16x32_bf16(
                            av[m][ks], bv[n][ks], acc1[m][n], 0, 0, 0);
            __builtin_amdgcn_s_setprio(0);
            LGKM0();                      // reads drained before overwrite
            BARR();
        }
#undef FSTG

        // epilogue: P = (acc1 + bias) * query -> bf16, XOR-swizzled LDS write
        // (P aliases B-buf0; all buf reads drained at loop exit)
#pragma unroll
        for (int m = 0; m < 2; ++m)
#pragma unroll
            for (int n = 0; n < 4; ++n) {
                const int cl   = wave * 64 + n * 16 + l16;   // 0..255
                const int gcol = nt * 256 + cl;
                const float bvv = bias[gcol];
#pragma unroll
                for (int j = 0; j < 4; ++j) {
                    const int row = m * 16 + lq * 4 + j;     // 0..31
                    float v = (acc1[m][n][j] + bvv) *
                              query[(size_t)(row0 + row) * C_ + gcol];
                    __hip_bfloat16 hb = __float2bfloat16(v);
                    *(uint16_t*)(Plds + row * 512 +
                                 ((cl * 2) ^ ((row & 7) << 4))) =
                        *(uint16_t*)&hb;
                }
            }
        LGKM0();
        BARR();                           // P complete

        // gemm2 pass: acc2 += P[32x256] @ W-slice[128 x 256]^T
#pragma unroll
        for (int kk = 0; kk < 8; ++kk) {
            bf16x8 pv[2], wv[2];
#pragma unroll
            for (int m = 0; m < 2; ++m) {
                const int r = m * 16 + l16;
                pv[m] = *(const bf16x8*)(Plds + r * 512 +
                    ((kk * 64 + lq * 16) ^ ((l16 & 7) << 4)));
            }
#pragma unroll
            for (int n = 0; n < 2; ++n) {
                const int wrow = wave * 32 + n * 16 + l16;   // 0..127
                wv[n] = *(const bf16x8*)(Wt + (size_t)wrow * C_ +
                                         nt * 256 + kk * 32 + lq * 8);
            }
#pragma unroll
            for (int m = 0; m < 2; ++m)
#pragma unroll
                for (int n = 0; n < 2; ++n)
                    acc2[m][n] = __builtin_amdgcn_mfma_f32_16x16x32_bf16(
                        pv[m], wv[n], acc2[m][n], 0, 0, 0);
        }
        LGKM0();
        BARR();                           // P reads done; next nt may overwrite
    }

    // finale: acc2 -> LG, then per-(row,h) double softmax -> filt
#pragma unroll
    for (int m = 0; m < 2; ++m)
#pragma unroll
        for (int n = 0; n < 2; ++n) {
            const int cl = wave * 32 + n * 16 + l16;
#pragma unroll
            for (int j = 0; j < 4; ++j) {
                const int row = m * 16 + lq * 4 + j;
                LG[row * 128 + cl] = acc2[m][n][j];
            }
        }
    LGKM0();
    BARR();

    for (int id = t; id < 32 * H_; id += 256) {
        const int row = id / H_;
        const int h   = id - row * H_;
        float v[KW];
#pragma unroll
        for (int k = 0; k < KW; ++k)
            v[k] = LG[row * 128 + h * KW + k] + attn_b[h * KW + k];
#pragma unroll
        for (int pass = 0; pass < 2; ++pass) {
            float mx = v[0];
#pragma unroll
            for (int k = 1; k < KW; ++k) mx = fmaxf(mx, v[k]);
            float s = 0.f;
#pragma unroll
            for (int k = 0; k < KW; ++k) { v[k] = __expf(v[k] - mx); s += v[k]; }
            float inv = 1.f / s;
#pragma unroll
            for (int k = 0; k < KW; ++k) v[k] *= inv;
        }
        const size_t base = ((size_t)(row0 + row) * H_ + h) * KW;
#pragma unroll
        for (int k = 0; k < KW; ++k) filt[base + k] = v[k];
    }
}

// ---------------------------------------------------------------------------
// Kernel 5: light conv, sliding-window version.
// ---------------------------------------------------------------------------
#define TSL 16
#define SCHK 256   // s per block (16 s-groups x TSL)

__global__ __launch_bounds__(256) void lightconv_kernel(
    const float* __restrict__ value, const float* __restrict__ filt,
    float* __restrict__ out)
{
    __shared__ float fl[SCHK * KW];   // 2304 floats

    const int tid = threadIdx.x;
    const int blk = blockIdx.x;                   // [0, 768)
    const int nSC = S_ / SCHK;                    // 8
    const int b   = blk / (H_ * nSC);
    const int rem = blk % (H_ * nSC);
    const int h   = rem / nSC;
    const int sch = rem % nSC;
    const int S0  = sch * SCHK;

    {
        const size_t r0 = ((size_t)b * S_ + S0) * H_ + h;   // filt row of s=S0
#pragma unroll
        for (int i = 0; i < 9; ++i) {
            int j  = tid + 256 * i;               // 0..2303
            int so = j / KW;
            int k  = j - so * KW;
            fl[j] = filt[(r0 + (size_t)so * H_) * KW + k];
        }
    }
    __syncthreads();

    const int d4 = tid & 15;
    const int sg = tid >> 4;                      // 0..15
    const int s0 = S0 + sg * TSL;
    const size_t vbase = (size_t)b * S_ * C_ + h * D_ + d4 * 4;
    const float* flrow = &fl[(sg * TSL) * KW];

    float4 win[KW];
#pragma unroll
    for (int k = 0; k < 8; ++k) {
        int sp = s0 + k - PADW;
        float4 v = {0.f, 0.f, 0.f, 0.f};
        if ((unsigned)sp < (unsigned)S_)
            v = *reinterpret_cast<const float4*>(&value[vbase + (size_t)sp * C_]);
        win[k] = v;
    }

#pragma unroll
    for (int i = 0; i < TSL; ++i) {
        int sp = s0 + i + PADW;
        float4 nv = {0.f, 0.f, 0.f, 0.f};
        if ((unsigned)sp < (unsigned)S_)
            nv = *reinterpret_cast<const float4*>(&value[vbase + (size_t)sp * C_]);
        win[8] = nv;

        float4 acc = {0.f, 0.f, 0.f, 0.f};
#pragma unroll
        for (int k = 0; k < KW; ++k) {
            float f = flrow[i * KW + k];
            acc.x += win[k].x * f;
            acc.y += win[k].y * f;
            acc.z += win[k].z * f;
            acc.w += win[k].w * f;
        }
        *reinterpret_cast<float4*>(&out[vbase + (size_t)(s0 + i) * C_]) = acc;

#pragma unroll
        for (int k = 0; k < 8; ++k) win[k] = win[k + 1];
    }
}

// ---------------------------------------------------------------------------
extern "C" void kernel_launch(void* const* d_in, const int* in_sizes, int n_in,
                              void* d_out, int out_size, void* d_ws, size_t ws_size,
                              hipStream_t stream)
{
    const float* query  = (const float*)d_in[0];
    const float* value  = (const float*)d_in[1];
    const float* hidden = (const float*)d_in[2];
    const float* dw_w   = (const float*)d_in[3];
    const float* pw_w   = (const float*)d_in[4];
    const float* sep_b  = (const float*)d_in[5];
    const float* attn_W = (const float*)d_in[6];
    const float* attn_b = (const float*)d_in[7];
    float* out = (float*)d_out;

    // workspace layout (all regions fully rewritten every call)
    char* ws = (char*)d_ws;
    __hip_bfloat16* dwb    = (__hip_bfloat16*)(ws);              // 25,165,824 B
    __hip_bfloat16* pwWb   = (__hip_bfloat16*)(ws + 25165824);   //  1,179,648 B
    __hip_bfloat16* attnWb = (__hip_bfloat16*)(ws + 26345472);   //    196,608 B
    float*          filt   = (float*)(ws + 26542080);            //  7,077,888 B
    // total: 33,619,968 B

    convert_w_kernel<<<(C_ * HID_) / 256, 256, 0, stream>>>(pw_w, attn_W, pwWb, attnWb);

    dwconv_kernel<<<(M_ * (HID_ / 4)) / (256 * TSD), 256, 0, stream>>>(hidden, dw_w, dwb);

    fused_gemm_kernel<<<M_ / 32, 256, 0, stream>>>(
        dwb, pwWb, attnWb, sep_b, query, attn_b, filt);

    lightconv_kernel<<<B_ * H_ * (S_ / SCHK), 256, 0, stream>>>(value, filt, out);
}